// Round 5
// baseline (3980.947 us; speedup 1.0000x reference)
//
#include <hip/hip_runtime.h>

// PlasticLSTM: T=256, B=32, I=128, H=256, 4H=1024, CLIP=2
// d_in: x[T,B,I], Wx[4H,I], bx[4H], Wh[4H,H], bh[4H], w_mod[1,H], b_mod[1],
//       w_fan[H,1], b_fan[H], alpha[H,H]   (all fp32)
// d_out: hs[T,B,H] ++ h[B,H] ++ c[B,H] ++ hebb[B,H,H]  (fp32, concat flat)

#define TT 256
#define BB 32
#define II 128
#define HH 256
#define G4 1024

typedef _Float16 h2_t __attribute__((ext_vector_type(2)));

__device__ __forceinline__ float sigm(float x) {
    return 1.0f / (1.0f + __expf(-x));
}
__device__ __forceinline__ float tanhfast(float x) {
    return 1.0f - 2.0f / (__expf(2.0f * x) + 1.0f);
}
__device__ __forceinline__ unsigned pkh(float lo, float hi) {
    h2_t v;
    v.x = (_Float16)lo;
    v.y = (_Float16)hi;
    return __builtin_bit_cast(unsigned, v);
}

#if __has_builtin(__builtin_amdgcn_fdot2)
__device__ __forceinline__ float dot2(unsigned a, unsigned b, float c) {
    return __builtin_amdgcn_fdot2(__builtin_bit_cast(h2_t, a),
                                  __builtin_bit_cast(h2_t, b), c, false);
}
#else
__device__ __forceinline__ float dot2(unsigned a, unsigned b, float c) {
    h2_t av = __builtin_bit_cast(h2_t, a), bv = __builtin_bit_cast(h2_t, b);
    return c + (float)av.x * (float)bv.x + (float)av.y * (float)bv.y;
}
#endif

__device__ __forceinline__ h2_t pkfma(h2_t a, h2_t b, h2_t c) {
#if __has_builtin(__builtin_elementwise_fma)
    return __builtin_elementwise_fma(a, b, c);
#else
    return a * b + c;
#endif
}
__device__ __forceinline__ h2_t clip2h(h2_t x) {
    const h2_t lo = {(_Float16)-2.0f, (_Float16)-2.0f};
    const h2_t hi = {(_Float16)2.0f, (_Float16)2.0f};
#if __has_builtin(__builtin_elementwise_max) && __has_builtin(__builtin_elementwise_min)
    return __builtin_elementwise_min(__builtin_elementwise_max(x, lo), hi);
#else
    h2_t r = x;
    r.x = r.x < lo.x ? lo.x : (r.x > hi.x ? hi.x : r.x);
    r.y = r.y < lo.y ? lo.y : (r.y > hi.y ? hi.y : r.y);
    return r;
#endif
}

// ---------------------------------------------------------------------------
// Wd3 layout: idx = ro*4096 + g*4 + ri  (ro in [0,8), ri in [0,4), g in [0,1024))
//   entry = uint4 of 8 f16 = Wh[g][8*r8 .. 8*r8+7], r8 = 4*ro + ri.
// ---------------------------------------------------------------------------
__global__ __launch_bounds__(256) void prep_wd3(const float* __restrict__ Wh,
                                                uint4* __restrict__ Wd3) {
    int idx = blockIdx.x * 256 + threadIdx.x;   // 32768
    int ro = idx >> 12, rem = idx & 4095;
    int g = rem >> 2, ri = rem & 3;
    int r8 = 4 * ro + ri;
    const float4* s = (const float4*)(Wh + (size_t)g * HH + (r8 << 3));
    float4 a = s[0], b2 = s[1];
    uint4 o;
    o.x = pkh(a.x, a.y);
    o.y = pkh(a.z, a.w);
    o.z = pkh(b2.x, b2.y);
    o.w = pkh(b2.z, b2.w);
    Wd3[idx] = o;
}

// ---------------------------------------------------------------------------
// alQ layout: idx = p4*256 + k  ->  uint4; component j = f16 pair
//   { alpha[2*(4*p4+j)][k], alpha[2*(4*p4+j)+1][k] }.
// ---------------------------------------------------------------------------
__global__ __launch_bounds__(256) void prep_alq(const float* __restrict__ alpha,
                                                uint4* __restrict__ alQ) {
    int idx = blockIdx.x * 256 + threadIdx.x;   // 8192
    int p4 = idx >> 8, k = idx & 255;
    uint4 o;
    unsigned r[4];
#pragma unroll
    for (int j = 0; j < 4; ++j) {
        int p = 4 * p4 + j;
        float a0 = alpha[(size_t)(2 * p) * HH + k];
        float a1 = alpha[(size_t)(2 * p + 1) * HH + k];
        r[j] = pkh(a0, a1);
    }
    o.x = r[0]; o.y = r[1]; o.z = r[2]; o.w = r[3];
    alQ[idx] = o;
}

// ---------------------------------------------------------------------------
// xf[t,b,g] = sum_i x[t,b,i]*Wx[g,i] + bx[g] + bh[g]
// ---------------------------------------------------------------------------
__global__ __launch_bounds__(256) void xf_gemm(const float* __restrict__ x,
                                               const float* __restrict__ Wx,
                                               const float* __restrict__ bx,
                                               const float* __restrict__ bh,
                                               float* __restrict__ xf) {
    __shared__ float As[64][37];
    __shared__ float Bs[64][37];
    const int tid = threadIdx.x;
    const int tx = tid & 15, ty = tid >> 4;
    const int m0 = blockIdx.y << 6;
    const int n0 = blockIdx.x << 6;
    float c[4][4] = {};

    for (int k0 = 0; k0 < II; k0 += 32) {
#pragma unroll
        for (int hh = 0; hh < 2; ++hh) {
            int row = (tid >> 3) + (hh << 5);
            int col = (tid & 7) << 2;
            float4 va = *(const float4*)(x + (size_t)(m0 + row) * II + k0 + col);
            As[row][col] = va.x; As[row][col + 1] = va.y;
            As[row][col + 2] = va.z; As[row][col + 3] = va.w;
            float4 vb = *(const float4*)(Wx + (size_t)(n0 + row) * II + k0 + col);
            Bs[row][col] = vb.x; Bs[row][col + 1] = vb.y;
            Bs[row][col + 2] = vb.z; Bs[row][col + 3] = vb.w;
        }
        __syncthreads();
#pragma unroll
        for (int kk = 0; kk < 32; ++kk) {
            float a[4], bb[4];
#pragma unroll
            for (int u = 0; u < 4; ++u) a[u] = As[(ty << 2) + u][kk];
#pragma unroll
            for (int v = 0; v < 4; ++v) bb[v] = Bs[(tx << 2) + v][kk];
#pragma unroll
            for (int u = 0; u < 4; ++u)
#pragma unroll
                for (int v = 0; v < 4; ++v)
                    c[u][v] = fmaf(a[u], bb[v], c[u][v]);
        }
        __syncthreads();
    }
    const int n = n0 + (tx << 2);
    float4 bxv = *(const float4*)(bx + n);
    float4 bhv = *(const float4*)(bh + n);
    float4 badd = {bxv.x + bhv.x, bxv.y + bhv.y, bxv.z + bhv.z, bxv.w + bhv.w};
#pragma unroll
    for (int u = 0; u < 4; ++u) {
        int m = m0 + (ty << 2) + u;
        float4 o = {c[u][0] + badd.x, c[u][1] + badd.y,
                    c[u][2] + badd.z, c[u][3] + badd.w};
        *(float4*)(xf + (size_t)m * G4 + n) = o;
    }
}

// ---------------------------------------------------------------------------
// hebb: 32 NAMED half2 registers per thread. alpha: 8 RESIDENT uint4 regs.
// Wd3 stream: rolling 2-buffer register prefetch (>=1 burst always in flight).
// ---------------------------------------------------------------------------
#define HBP_FOREACH(X) \
    X(0) X(1) X(2) X(3) X(4) X(5) X(6) X(7) \
    X(8) X(9) X(10) X(11) X(12) X(13) X(14) X(15) \
    X(16) X(17) X(18) X(19) X(20) X(21) X(22) X(23) \
    X(24) X(25) X(26) X(27) X(28) X(29) X(30) X(31)

#define HBP_DECL(i) h2_t hp##i = {(_Float16)0.0f, (_Float16)0.0f};
#define HBP_OUT(i) \
    hbout[(size_t)(r0 + 2 * i) * HH + k]     = (float)hp##i.x; \
    hbout[(size_t)(r0 + 2 * i + 1) * HH + k] = (float)hp##i.y;

#define HBP_STEP(i, au, hou, hnu) { \
    h2_t al2 = __builtin_bit_cast(h2_t, au); \
    h2_t ho2 = __builtin_bit_cast(h2_t, hou); \
    h2_t hn2 = __builtin_bit_cast(h2_t, hnu); \
    hp##i = clip2h(pkfma(mj2, ho2, hp##i)); \
    h2_t hna = hn2 * al2; \
    pp = dot2(__builtin_bit_cast(unsigned, hna), \
              __builtin_bit_cast(unsigned, hp##i), pp); }

// AV is a resident uint4 register
#define HBP_CHUNK(q, AV, i0, i1, i2, i3) { \
    uint4 ho = hfO4[hq0 + (q)]; \
    uint4 hn = hfN4[hq0 + (q)]; \
    HBP_STEP(i0, AV.x, ho.x, hn.x) \
    HBP_STEP(i1, AV.y, ho.y, hn.y) \
    HBP_STEP(i2, AV.z, ho.z, hn.z) \
    HBP_STEP(i3, AV.w, ho.w, hn.w) }

#define HBP_ALL_CHUNKS \
    HBP_CHUNK(0, aq0, 0, 1, 2, 3)     HBP_CHUNK(1, aq1, 4, 5, 6, 7) \
    HBP_CHUNK(2, aq2, 8, 9, 10, 11)   HBP_CHUNK(3, aq3, 12, 13, 14, 15) \
    HBP_CHUNK(4, aq4, 16, 17, 18, 19) HBP_CHUNK(5, aq5, 20, 21, 22, 23) \
    HBP_CHUNK(6, aq6, 24, 25, 26, 27) HBP_CHUNK(7, aq7, 28, 29, 30, 31)

// final deferred update only (no plast)
#define HBU_STEP(i, hou) { \
    h2_t ho2 = __builtin_bit_cast(h2_t, hou); \
    hp##i = clip2h(pkfma(mj2, ho2, hp##i)); }
#define HBU_CHUNK(q, i0, i1, i2, i3) { \
    uint4 ho = hfO4[hq0 + (q)]; \
    HBU_STEP(i0, ho.x) HBU_STEP(i1, ho.y) \
    HBU_STEP(i2, ho.z) HBU_STEP(i3, ho.w) }
#define HBU_ALL_CHUNKS \
    HBU_CHUNK(0, 0, 1, 2, 3)     HBU_CHUNK(1, 4, 5, 6, 7) \
    HBU_CHUNK(2, 8, 9, 10, 11)   HBU_CHUNK(3, 12, 13, 14, 15) \
    HBU_CHUNK(4, 16, 17, 18, 19) HBU_CHUNK(5, 20, 21, 22, 23) \
    HBU_CHUNK(6, 24, 25, 26, 27) HBU_CHUNK(7, 28, 29, 30, 31)

// prefetch weight chunk ro into 4 uint4 regs
#define PREF(B0, B1, B2, B3, ro) { \
    const uint4* _wp = wbase + ((size_t)(ro) << 12); \
    B0 = _wp[0]; B1 = _wp[1]; B2 = _wp[2]; B3 = _wp[3]; }

// consume weight chunk (16 dot2 against LDS h, uniform-address broadcasts)
#define PROC(W0, W1, W2, W3, ro) { \
    uint4 h0 = hfN4[4 * (ro)], h1 = hfN4[4 * (ro) + 1]; \
    uint4 h2 = hfN4[4 * (ro) + 2], h3 = hfN4[4 * (ro) + 3]; \
    ac0 = dot2(W0.x, h0.x, ac0); ac1 = dot2(W0.y, h0.y, ac1); \
    ac2 = dot2(W0.z, h0.z, ac2); ac3 = dot2(W0.w, h0.w, ac3); \
    ac0 = dot2(W1.x, h1.x, ac0); ac1 = dot2(W1.y, h1.y, ac1); \
    ac2 = dot2(W1.z, h1.z, ac2); ac3 = dot2(W1.w, h1.w, ac3); \
    ac0 = dot2(W2.x, h2.x, ac0); ac1 = dot2(W2.y, h2.y, ac1); \
    ac2 = dot2(W2.z, h2.z, ac2); ac3 = dot2(W2.w, h2.w, ac3); \
    ac0 = dot2(W3.x, h3.x, ac0); ac1 = dot2(W3.y, h3.y, ac1); \
    ac2 = dot2(W3.z, h3.z, ac2); ac3 = dot2(W3.w, h3.w, ac3); }

__global__ __launch_bounds__(1024, 1) void scan_kernel(
    const float* __restrict__ xf,      // [T,B,4H], biases folded
    const uint4* __restrict__ Wd3,     // f16 tiled Wh
    const uint4* __restrict__ alQ,     // f16 pair-packed alpha
    const float* __restrict__ w_mod,
    const float* __restrict__ b_mod,
    const float* __restrict__ w_fan,
    const float* __restrict__ b_fan,
    float* __restrict__ out) {
    const int b   = blockIdx.x;
    const int tid = threadIdx.x;
    const int k   = tid & (HH - 1);
    const int rg  = tid >> 8;        // 0..3
    const int r0  = rg << 6;
    const int hq0 = rg << 3;         // uint4 index of row r0 in hf_s

    __shared__ alignas(16) unsigned short hf_s[2][HH];
    __shared__ float fioj_s[G4];
    __shared__ float pp_s[4][HH];
    __shared__ float red_s[4];

    HBP_FOREACH(HBP_DECL)

    if (tid < HH) {
        hf_s[0][tid] = 0;
        hf_s[1][tid] = 0;
    }
    if (tid < 4) red_s[tid] = 0.0f;
    __syncthreads();

    const float bmod = b_mod[0];
    const float wf = w_fan[k], bf = b_fan[k], wm = w_mod[k];
    float creg = 0.0f, jreg = 0.0f, hnreg = 0.0f;

    const uint4* wbase = Wd3 + ((size_t)tid << 2);
    const uint4* aqp   = alQ + ((size_t)(rg << 3) << 8) + k;
    const float* xfp   = xf + (size_t)b * G4 + tid;

    // ---- Step-invariant alpha: 8 resident uint4 registers ----------------
    uint4 aq0 = aqp[0 << 8], aq1 = aqp[1 << 8], aq2 = aqp[2 << 8],
          aq3 = aqp[3 << 8], aq4 = aqp[4 << 8], aq5 = aqp[5 << 8],
          aq6 = aqp[6 << 8], aq7 = aqp[7 << 8];

    for (int t = 0; t < TT; ++t) {
        float xfv = xfp[(size_t)t * BB * G4];   // in flight across phase 1a

        // weight chunk 0 in flight across all of phase 1a
        uint4 pb0, pb1, pb2, pb3, pc0, pc1, pc2, pc3;
        PREF(pb0, pb1, pb2, pb3, 0)

        // ---- Phase 1a: eta_{t-1}; deferred hebb update + plast(t) fused ---
        float eta = tanhfast(((red_s[0] + red_s[1]) + (red_s[2] + red_s[3])) + bmod);
        float mj = fmaf(eta, wf, bf) * jreg;    // 0 at t=0
        h2_t mj2;
        mj2.x = (_Float16)mj;
        mj2.y = mj2.x;
        const uint4* hfO4 = (const uint4*)hf_s[t & 1];        // h_{t-2}
        const uint4* hfN4 = (const uint4*)hf_s[(t & 1) ^ 1];  // h_{t-1}
        float pp = 0.0f;
        HBP_ALL_CHUNKS
        pp_s[rg][k] = pp;

        // ---- Phase 1b: gate matvec, rolling 2-buffer prefetch -------------
        float ac0 = 0.f, ac1 = 0.f, ac2 = 0.f, ac3 = 0.f;
        PREF(pc0, pc1, pc2, pc3, 1)
        PROC(pb0, pb1, pb2, pb3, 0)
        PREF(pb0, pb1, pb2, pb3, 2)
        PROC(pc0, pc1, pc2, pc3, 1)
        PREF(pc0, pc1, pc2, pc3, 3)
        PROC(pb0, pb1, pb2, pb3, 2)
        PREF(pb0, pb1, pb2, pb3, 4)
        PROC(pc0, pc1, pc2, pc3, 3)
        PREF(pc0, pc1, pc2, pc3, 5)
        PROC(pb0, pb1, pb2, pb3, 4)
        PREF(pb0, pb1, pb2, pb3, 6)
        PROC(pc0, pc1, pc2, pc3, 5)
        PREF(pc0, pc1, pc2, pc3, 7)
        PROC(pb0, pb1, pb2, pb3, 6)
        PROC(pc0, pc1, pc2, pc3, 7)
        fioj_s[tid] = ((ac0 + ac1) + (ac2 + ac3)) + xfv;
        __syncthreads();

        // ---- Phase 2: cell update, redundant across the 4 row-groups ------
        float fg = sigm(fioj_s[k]);
        float ig = sigm(fioj_s[HH + k]);
        float og = sigm(fioj_s[2 * HH + k]);
        float jp = fioj_s[3 * HH + k]
                 + ((pp_s[0][k] + pp_s[1][k]) + (pp_s[2][k] + pp_s[3][k]));
        jreg = tanhfast(jp);
        creg = fmaf(fg, creg, ig * jreg);
        hnreg = og * tanhfast(creg);
        if (rg == 0) {   // waves 0-3, wave-uniform
            _Float16 hh = (_Float16)hnreg;
            hf_s[t & 1][k] = __builtin_bit_cast(unsigned short, hh);
            out[((size_t)t * BB + b) * HH + k] = hnreg;
            float e = creg * wm;
#pragma unroll
            for (int m = 32; m >= 1; m >>= 1) e += __shfl_xor(e, m, 64);
            if ((k & 63) == 0) red_s[k >> 6] = e;
        }
        __syncthreads();
    }

    // ---- Final deferred hebb update (step 255's delta) -------------------
    {
        float eta = tanhfast(((red_s[0] + red_s[1]) + (red_s[2] + red_s[3])) + bmod);
        float mj = fmaf(eta, wf, bf) * jreg;
        h2_t mj2;
        mj2.x = (_Float16)mj;
        mj2.y = mj2.x;
        const uint4* hfO4 = (const uint4*)hf_s[0];   // h_254 (TT even)
        HBU_ALL_CHUNKS
    }

    const size_t HS = (size_t)TT * BB * HH;
    if (rg == 0) {
        out[HS + (size_t)b * HH + k]           = hnreg;  // h_255
        out[HS + BB * HH + (size_t)b * HH + k] = creg;   // c_255
    }
    float* hbout = out + HS + 2 * BB * HH + (size_t)b * HH * HH;
    HBP_FOREACH(HBP_OUT)
}

// ---------------------------------------------------------------------------
extern "C" void kernel_launch(void* const* d_in, const int* in_sizes, int n_in,
                              void* d_out, int out_size, void* d_ws,
                              size_t ws_size, hipStream_t stream) {
    const float* x     = (const float*)d_in[0];
    const float* Wx    = (const float*)d_in[1];
    const float* bx    = (const float*)d_in[2];
    const float* Wh    = (const float*)d_in[3];
    const float* bh    = (const float*)d_in[4];
    const float* w_mod = (const float*)d_in[5];
    const float* b_mod = (const float*)d_in[6];
    const float* w_fan = (const float*)d_in[7];
    const float* b_fan = (const float*)d_in[8];
    const float* alpha = (const float*)d_in[9];
    float* out = (float*)d_out;

    float* xf  = (float*)d_ws;                                   // 32 MiB
    uint4* Wd3 = (uint4*)((char*)d_ws + 33554432);                // 512 KiB
    uint4* alQ = (uint4*)((char*)d_ws + 33554432 + 524288);       // 128 KiB

    hipLaunchKernelGGL(prep_wd3, dim3(128), dim3(256), 0, stream, Wh, Wd3);
    hipLaunchKernelGGL(prep_alq, dim3(32), dim3(256), 0, stream, alpha, alQ);
    hipLaunchKernelGGL(xf_gemm, dim3(16, 128), dim3(256), 0, stream,
                       x, Wx, bx, bh, xf);
    hipLaunchKernelGGL(scan_kernel, dim3(BB), dim3(1024), 0, stream,
                       xf, Wd3, alQ, w_mod, b_mod, w_fan, b_fan, out);
}

// Round 6
// 3964.470 us; speedup vs baseline: 1.0042x; 1.0042x over previous
//
#include <hip/hip_runtime.h>

// PlasticLSTM: T=256, B=32, I=128, H=256, 4H=1024, CLIP=2
// d_in: x[T,B,I], Wx[4H,I], bx[4H], Wh[4H,H], bh[4H], w_mod[1,H], b_mod[1],
//       w_fan[H,1], b_fan[H], alpha[H,H]   (all fp32)
// d_out: hs[T,B,H] ++ h[B,H] ++ c[B,H] ++ hebb[B,H,H]  (fp32, concat flat)

#define TT 256
#define BB 32
#define II 128
#define HH 256
#define G4 1024

typedef _Float16 h2_t __attribute__((ext_vector_type(2)));

__device__ __forceinline__ float sigm(float x) {
    return 1.0f / (1.0f + __expf(-x));
}
__device__ __forceinline__ float tanhfast(float x) {
    return 1.0f - 2.0f / (__expf(2.0f * x) + 1.0f);
}
__device__ __forceinline__ unsigned pkh(float lo, float hi) {
    h2_t v;
    v.x = (_Float16)lo;
    v.y = (_Float16)hi;
    return __builtin_bit_cast(unsigned, v);
}

#if __has_builtin(__builtin_amdgcn_fdot2)
__device__ __forceinline__ float dot2(unsigned a, unsigned b, float c) {
    return __builtin_amdgcn_fdot2(__builtin_bit_cast(h2_t, a),
                                  __builtin_bit_cast(h2_t, b), c, false);
}
#else
__device__ __forceinline__ float dot2(unsigned a, unsigned b, float c) {
    h2_t av = __builtin_bit_cast(h2_t, a), bv = __builtin_bit_cast(h2_t, b);
    return c + (float)av.x * (float)bv.x + (float)av.y * (float)bv.y;
}
#endif

__device__ __forceinline__ h2_t pkfma(h2_t a, h2_t b, h2_t c) {
#if __has_builtin(__builtin_elementwise_fma)
    return __builtin_elementwise_fma(a, b, c);
#else
    return a * b + c;
#endif
}
__device__ __forceinline__ h2_t clip2h(h2_t x) {
    const h2_t lo = {(_Float16)-2.0f, (_Float16)-2.0f};
    const h2_t hi = {(_Float16)2.0f, (_Float16)2.0f};
#if __has_builtin(__builtin_elementwise_max) && __has_builtin(__builtin_elementwise_min)
    return __builtin_elementwise_min(__builtin_elementwise_max(x, lo), hi);
#else
    h2_t r = x;
    r.x = r.x < lo.x ? lo.x : (r.x > hi.x ? hi.x : r.x);
    r.y = r.y < lo.y ? lo.y : (r.y > hi.y ? hi.y : r.y);
    return r;
#endif
}

// ---------------------------------------------------------------------------
// Wd3 layout: idx = ro*4096 + g*4 + ri  (ro in [0,8), ri in [0,4), g in [0,1024))
//   entry = uint4 of 8 f16 = Wh[g][8*r8 .. 8*r8+7], r8 = 4*ro + ri.
// ---------------------------------------------------------------------------
__global__ __launch_bounds__(256) void prep_wd3(const float* __restrict__ Wh,
                                                uint4* __restrict__ Wd3) {
    int idx = blockIdx.x * 256 + threadIdx.x;   // 32768
    int ro = idx >> 12, rem = idx & 4095;
    int g = rem >> 2, ri = rem & 3;
    int r8 = 4 * ro + ri;
    const float4* s = (const float4*)(Wh + (size_t)g * HH + (r8 << 3));
    float4 a = s[0], b2 = s[1];
    uint4 o;
    o.x = pkh(a.x, a.y);
    o.y = pkh(a.z, a.w);
    o.z = pkh(b2.x, b2.y);
    o.w = pkh(b2.z, b2.w);
    Wd3[idx] = o;
}

// ---------------------------------------------------------------------------
// alQ layout: idx = p4*256 + k  ->  uint4; component j = f16 pair
//   { alpha[2*(4*p4+j)][k], alpha[2*(4*p4+j)+1][k] }.
// ---------------------------------------------------------------------------
__global__ __launch_bounds__(256) void prep_alq(const float* __restrict__ alpha,
                                                uint4* __restrict__ alQ) {
    int idx = blockIdx.x * 256 + threadIdx.x;   // 8192
    int p4 = idx >> 8, k = idx & 255;
    uint4 o;
    unsigned r[4];
#pragma unroll
    for (int j = 0; j < 4; ++j) {
        int p = 4 * p4 + j;
        float a0 = alpha[(size_t)(2 * p) * HH + k];
        float a1 = alpha[(size_t)(2 * p + 1) * HH + k];
        r[j] = pkh(a0, a1);
    }
    o.x = r[0]; o.y = r[1]; o.z = r[2]; o.w = r[3];
    alQ[idx] = o;
}

// ---------------------------------------------------------------------------
// xf[t,b,g] = sum_i x[t,b,i]*Wx[g,i] + bx[g] + bh[g]
// ---------------------------------------------------------------------------
__global__ __launch_bounds__(256) void xf_gemm(const float* __restrict__ x,
                                               const float* __restrict__ Wx,
                                               const float* __restrict__ bx,
                                               const float* __restrict__ bh,
                                               float* __restrict__ xf) {
    __shared__ float As[64][37];
    __shared__ float Bs[64][37];
    const int tid = threadIdx.x;
    const int tx = tid & 15, ty = tid >> 4;
    const int m0 = blockIdx.y << 6;
    const int n0 = blockIdx.x << 6;
    float c[4][4] = {};

    for (int k0 = 0; k0 < II; k0 += 32) {
#pragma unroll
        for (int hh = 0; hh < 2; ++hh) {
            int row = (tid >> 3) + (hh << 5);
            int col = (tid & 7) << 2;
            float4 va = *(const float4*)(x + (size_t)(m0 + row) * II + k0 + col);
            As[row][col] = va.x; As[row][col + 1] = va.y;
            As[row][col + 2] = va.z; As[row][col + 3] = va.w;
            float4 vb = *(const float4*)(Wx + (size_t)(n0 + row) * II + k0 + col);
            Bs[row][col] = vb.x; Bs[row][col + 1] = vb.y;
            Bs[row][col + 2] = vb.z; Bs[row][col + 3] = vb.w;
        }
        __syncthreads();
#pragma unroll
        for (int kk = 0; kk < 32; ++kk) {
            float a[4], bb[4];
#pragma unroll
            for (int u = 0; u < 4; ++u) a[u] = As[(ty << 2) + u][kk];
#pragma unroll
            for (int v = 0; v < 4; ++v) bb[v] = Bs[(tx << 2) + v][kk];
#pragma unroll
            for (int u = 0; u < 4; ++u)
#pragma unroll
                for (int v = 0; v < 4; ++v)
                    c[u][v] = fmaf(a[u], bb[v], c[u][v]);
        }
        __syncthreads();
    }
    const int n = n0 + (tx << 2);
    float4 bxv = *(const float4*)(bx + n);
    float4 bhv = *(const float4*)(bh + n);
    float4 badd = {bxv.x + bhv.x, bxv.y + bhv.y, bxv.z + bhv.z, bxv.w + bhv.w};
#pragma unroll
    for (int u = 0; u < 4; ++u) {
        int m = m0 + (ty << 2) + u;
        float4 o = {c[u][0] + badd.x, c[u][1] + badd.y,
                    c[u][2] + badd.z, c[u][3] + badd.w};
        *(float4*)(xf + (size_t)m * G4 + n) = o;
    }
}

// ---------------------------------------------------------------------------
// hebb: 32 NAMED half2 registers per thread. alpha: 8 RESIDENT uint4 regs.
// Wd3 stream: rolling 2-buffer register prefetch.
// amdgpu_waves_per_eu(4,4): grid is 32 blocks -> exactly 1 block/CU; pin the
// allocator's budget at 512/4 = 128 VGPRs (default heuristic picked 64 and
// spilled alpha+prefetch to scratch in round 5: WRITE_SIZE 17.2->32.6 MB).
// ---------------------------------------------------------------------------
#define HBP_FOREACH(X) \
    X(0) X(1) X(2) X(3) X(4) X(5) X(6) X(7) \
    X(8) X(9) X(10) X(11) X(12) X(13) X(14) X(15) \
    X(16) X(17) X(18) X(19) X(20) X(21) X(22) X(23) \
    X(24) X(25) X(26) X(27) X(28) X(29) X(30) X(31)

#define HBP_DECL(i) h2_t hp##i = {(_Float16)0.0f, (_Float16)0.0f};
#define HBP_OUT(i) \
    hbout[(size_t)(r0 + 2 * i) * HH + k]     = (float)hp##i.x; \
    hbout[(size_t)(r0 + 2 * i + 1) * HH + k] = (float)hp##i.y;

#define HBP_STEP(i, au, hou, hnu) { \
    h2_t al2 = __builtin_bit_cast(h2_t, au); \
    h2_t ho2 = __builtin_bit_cast(h2_t, hou); \
    h2_t hn2 = __builtin_bit_cast(h2_t, hnu); \
    hp##i = clip2h(pkfma(mj2, ho2, hp##i)); \
    h2_t hna = hn2 * al2; \
    pp = dot2(__builtin_bit_cast(unsigned, hna), \
              __builtin_bit_cast(unsigned, hp##i), pp); }

// AV is a resident uint4 register
#define HBP_CHUNK(q, AV, i0, i1, i2, i3) { \
    uint4 ho = hfO4[hq0 + (q)]; \
    uint4 hn = hfN4[hq0 + (q)]; \
    HBP_STEP(i0, AV.x, ho.x, hn.x) \
    HBP_STEP(i1, AV.y, ho.y, hn.y) \
    HBP_STEP(i2, AV.z, ho.z, hn.z) \
    HBP_STEP(i3, AV.w, ho.w, hn.w) }

#define HBP_ALL_CHUNKS \
    HBP_CHUNK(0, aq0, 0, 1, 2, 3)     HBP_CHUNK(1, aq1, 4, 5, 6, 7) \
    HBP_CHUNK(2, aq2, 8, 9, 10, 11)   HBP_CHUNK(3, aq3, 12, 13, 14, 15) \
    HBP_CHUNK(4, aq4, 16, 17, 18, 19) HBP_CHUNK(5, aq5, 20, 21, 22, 23) \
    HBP_CHUNK(6, aq6, 24, 25, 26, 27) HBP_CHUNK(7, aq7, 28, 29, 30, 31)

// final deferred update only (no plast)
#define HBU_STEP(i, hou) { \
    h2_t ho2 = __builtin_bit_cast(h2_t, hou); \
    hp##i = clip2h(pkfma(mj2, ho2, hp##i)); }
#define HBU_CHUNK(q, i0, i1, i2, i3) { \
    uint4 ho = hfO4[hq0 + (q)]; \
    HBU_STEP(i0, ho.x) HBU_STEP(i1, ho.y) \
    HBU_STEP(i2, ho.z) HBU_STEP(i3, ho.w) }
#define HBU_ALL_CHUNKS \
    HBU_CHUNK(0, 0, 1, 2, 3)     HBU_CHUNK(1, 4, 5, 6, 7) \
    HBU_CHUNK(2, 8, 9, 10, 11)   HBU_CHUNK(3, 12, 13, 14, 15) \
    HBU_CHUNK(4, 16, 17, 18, 19) HBU_CHUNK(5, 20, 21, 22, 23) \
    HBU_CHUNK(6, 24, 25, 26, 27) HBU_CHUNK(7, 28, 29, 30, 31)

// prefetch weight chunk ro into 4 uint4 regs
#define PREF(B0, B1, B2, B3, ro) { \
    const uint4* _wp = wbase + ((size_t)(ro) << 12); \
    B0 = _wp[0]; B1 = _wp[1]; B2 = _wp[2]; B3 = _wp[3]; }

// consume weight chunk (16 dot2 against LDS h, uniform-address broadcasts)
#define PROC(W0, W1, W2, W3, ro) { \
    uint4 h0 = hfN4[4 * (ro)], h1 = hfN4[4 * (ro) + 1]; \
    uint4 h2 = hfN4[4 * (ro) + 2], h3 = hfN4[4 * (ro) + 3]; \
    ac0 = dot2(W0.x, h0.x, ac0); ac1 = dot2(W0.y, h0.y, ac1); \
    ac2 = dot2(W0.z, h0.z, ac2); ac3 = dot2(W0.w, h0.w, ac3); \
    ac0 = dot2(W1.x, h1.x, ac0); ac1 = dot2(W1.y, h1.y, ac1); \
    ac2 = dot2(W1.z, h1.z, ac2); ac3 = dot2(W1.w, h1.w, ac3); \
    ac0 = dot2(W2.x, h2.x, ac0); ac1 = dot2(W2.y, h2.y, ac1); \
    ac2 = dot2(W2.z, h2.z, ac2); ac3 = dot2(W2.w, h2.w, ac3); \
    ac0 = dot2(W3.x, h3.x, ac0); ac1 = dot2(W3.y, h3.y, ac1); \
    ac2 = dot2(W3.z, h3.z, ac2); ac3 = dot2(W3.w, h3.w, ac3); }

__global__ __launch_bounds__(1024)
__attribute__((amdgpu_waves_per_eu(4, 4)))
void scan_kernel(
    const float* __restrict__ xf,      // [T,B,4H], biases folded
    const uint4* __restrict__ Wd3,     // f16 tiled Wh
    const uint4* __restrict__ alQ,     // f16 pair-packed alpha
    const float* __restrict__ w_mod,
    const float* __restrict__ b_mod,
    const float* __restrict__ w_fan,
    const float* __restrict__ b_fan,
    float* __restrict__ out) {
    const int b   = blockIdx.x;
    const int tid = threadIdx.x;
    const int k   = tid & (HH - 1);
    const int rg  = tid >> 8;        // 0..3
    const int r0  = rg << 6;
    const int hq0 = rg << 3;         // uint4 index of row r0 in hf_s

    __shared__ alignas(16) unsigned short hf_s[2][HH];
    __shared__ float fioj_s[G4];
    __shared__ float pp_s[4][HH];
    __shared__ float red_s[4];

    HBP_FOREACH(HBP_DECL)

    if (tid < HH) {
        hf_s[0][tid] = 0;
        hf_s[1][tid] = 0;
    }
    if (tid < 4) red_s[tid] = 0.0f;
    __syncthreads();

    const float bmod = b_mod[0];
    const float wf = w_fan[k], bf = b_fan[k], wm = w_mod[k];
    float creg = 0.0f, jreg = 0.0f, hnreg = 0.0f;

    const uint4* wbase = Wd3 + ((size_t)tid << 2);
    const uint4* aqp   = alQ + ((size_t)(rg << 3) << 8) + k;
    const float* xfp   = xf + (size_t)b * G4 + tid;

    // ---- Step-invariant alpha: 8 resident uint4 registers ----------------
    uint4 aq0 = aqp[0 << 8], aq1 = aqp[1 << 8], aq2 = aqp[2 << 8],
          aq3 = aqp[3 << 8], aq4 = aqp[4 << 8], aq5 = aqp[5 << 8],
          aq6 = aqp[6 << 8], aq7 = aqp[7 << 8];

    for (int t = 0; t < TT; ++t) {
        float xfv = xfp[(size_t)t * BB * G4];   // in flight across phase 1a

        // weight chunk 0 in flight across all of phase 1a
        uint4 pb0, pb1, pb2, pb3, pc0, pc1, pc2, pc3;
        PREF(pb0, pb1, pb2, pb3, 0)

        // ---- Phase 1a: eta_{t-1}; deferred hebb update + plast(t) fused ---
        float eta = tanhfast(((red_s[0] + red_s[1]) + (red_s[2] + red_s[3])) + bmod);
        float mj = fmaf(eta, wf, bf) * jreg;    // 0 at t=0
        h2_t mj2;
        mj2.x = (_Float16)mj;
        mj2.y = mj2.x;
        const uint4* hfO4 = (const uint4*)hf_s[t & 1];        // h_{t-2}
        const uint4* hfN4 = (const uint4*)hf_s[(t & 1) ^ 1];  // h_{t-1}
        float pp = 0.0f;
        HBP_ALL_CHUNKS
        pp_s[rg][k] = pp;

        // ---- Phase 1b: gate matvec, rolling 2-buffer prefetch -------------
        float ac0 = 0.f, ac1 = 0.f, ac2 = 0.f, ac3 = 0.f;
        PREF(pc0, pc1, pc2, pc3, 1)
        PROC(pb0, pb1, pb2, pb3, 0)
        PREF(pb0, pb1, pb2, pb3, 2)
        PROC(pc0, pc1, pc2, pc3, 1)
        PREF(pc0, pc1, pc2, pc3, 3)
        PROC(pb0, pb1, pb2, pb3, 2)
        PREF(pb0, pb1, pb2, pb3, 4)
        PROC(pc0, pc1, pc2, pc3, 3)
        PREF(pc0, pc1, pc2, pc3, 5)
        PROC(pb0, pb1, pb2, pb3, 4)
        PREF(pb0, pb1, pb2, pb3, 6)
        PROC(pc0, pc1, pc2, pc3, 5)
        PREF(pc0, pc1, pc2, pc3, 7)
        PROC(pb0, pb1, pb2, pb3, 6)
        PROC(pc0, pc1, pc2, pc3, 7)
        fioj_s[tid] = ((ac0 + ac1) + (ac2 + ac3)) + xfv;
        __syncthreads();

        // ---- Phase 2: cell update, redundant across the 4 row-groups ------
        float fg = sigm(fioj_s[k]);
        float ig = sigm(fioj_s[HH + k]);
        float og = sigm(fioj_s[2 * HH + k]);
        float jp = fioj_s[3 * HH + k]
                 + ((pp_s[0][k] + pp_s[1][k]) + (pp_s[2][k] + pp_s[3][k]));
        jreg = tanhfast(jp);
        creg = fmaf(fg, creg, ig * jreg);
        hnreg = og * tanhfast(creg);
        if (rg == 0) {   // waves 0-3, wave-uniform
            _Float16 hh = (_Float16)hnreg;
            hf_s[t & 1][k] = __builtin_bit_cast(unsigned short, hh);
            out[((size_t)t * BB + b) * HH + k] = hnreg;
            float e = creg * wm;
#pragma unroll
            for (int m = 32; m >= 1; m >>= 1) e += __shfl_xor(e, m, 64);
            if ((k & 63) == 0) red_s[k >> 6] = e;
        }
        __syncthreads();
    }

    // ---- Final deferred hebb update (step 255's delta) -------------------
    {
        float eta = tanhfast(((red_s[0] + red_s[1]) + (red_s[2] + red_s[3])) + bmod);
        float mj = fmaf(eta, wf, bf) * jreg;
        h2_t mj2;
        mj2.x = (_Float16)mj;
        mj2.y = mj2.x;
        const uint4* hfO4 = (const uint4*)hf_s[0];   // h_254 (TT even)
        HBU_ALL_CHUNKS
    }

    const size_t HS = (size_t)TT * BB * HH;
    if (rg == 0) {
        out[HS + (size_t)b * HH + k]           = hnreg;  // h_255
        out[HS + BB * HH + (size_t)b * HH + k] = creg;   // c_255
    }
    float* hbout = out + HS + 2 * BB * HH + (size_t)b * HH * HH;
    HBP_FOREACH(HBP_OUT)
}

// ---------------------------------------------------------------------------
extern "C" void kernel_launch(void* const* d_in, const int* in_sizes, int n_in,
                              void* d_out, int out_size, void* d_ws,
                              size_t ws_size, hipStream_t stream) {
    const float* x     = (const float*)d_in[0];
    const float* Wx    = (const float*)d_in[1];
    const float* bx    = (const float*)d_in[2];
    const float* Wh    = (const float*)d_in[3];
    const float* bh    = (const float*)d_in[4];
    const float* w_mod = (const float*)d_in[5];
    const float* b_mod = (const float*)d_in[6];
    const float* w_fan = (const float*)d_in[7];
    const float* b_fan = (const float*)d_in[8];
    const float* alpha = (const float*)d_in[9];
    float* out = (float*)d_out;

    float* xf  = (float*)d_ws;                                   // 32 MiB
    uint4* Wd3 = (uint4*)((char*)d_ws + 33554432);                // 512 KiB
    uint4* alQ = (uint4*)((char*)d_ws + 33554432 + 524288);       // 128 KiB

    hipLaunchKernelGGL(prep_wd3, dim3(128), dim3(256), 0, stream, Wh, Wd3);
    hipLaunchKernelGGL(prep_alq, dim3(32), dim3(256), 0, stream, alpha, alQ);
    hipLaunchKernelGGL(xf_gemm, dim3(16, 128), dim3(256), 0, stream,
                       x, Wx, bx, bh, xf);
    hipLaunchKernelGGL(scan_kernel, dim3(BB), dim3(1024), 0, stream,
                       xf, Wd3, alQ, w_mod, b_mod, w_fan, b_fan, out);
}